// Round 5
// baseline (248.532 us; speedup 1.0000x reference)
//
#include <hip/hip_runtime.h>
#include <hip/hip_bf16.h>
#include <stdint.h>

// Problem constants (all inputs & output are FP32 per the reference file)
#define BATCH 128
#define LAT   2000
#define NG    10000
#define KW    20
#define OUTW  (NG * KW)   // 200000
#define EPSV  1e-5f

// GEMM decomposition: 625 group-tiles (16 groups) x 7 k-splits; one wave per
// (tile, split); 9 k-chunks of 32 per split (63 chunks = 2016 >= 2000,
// tail zero-padded by predication). No LDS, no barriers.
#define KSPL  7
#define CPS   9
#define NTILE 625

typedef __bf16 bf16x8 __attribute__((ext_vector_type(8)));
typedef float  f32x4  __attribute__((ext_vector_type(4)));

__device__ __forceinline__ ushort f2bf(float f) {
  uint32_t u = __builtin_bit_cast(uint32_t, f);
  u = (u + 0x7FFFu + ((u >> 16) & 1u)) >> 16;  // RNE
  return (ushort)u;
}
__device__ __forceinline__ float bf2f(ushort h) {
  uint32_t u = ((uint32_t)h) << 16;
  return __builtin_bit_cast(float, u);
}

__device__ __forceinline__ int4 pack8(const float* p) {
  float4 f0 = *(const float4*)p;
  float4 f1 = *(const float4*)(p + 4);
  int4 v;
  v.x = (int)((uint32_t)f2bf(f0.x) | ((uint32_t)f2bf(f0.y) << 16));
  v.y = (int)((uint32_t)f2bf(f0.z) | ((uint32_t)f2bf(f0.w) << 16));
  v.z = (int)((uint32_t)f2bf(f1.x) | ((uint32_t)f2bf(f1.y) << 16));
  v.w = (int)((uint32_t)f2bf(f1.z) | ((uint32_t)f2bf(f1.w) << 16));
  return v;
}

// =====================================================================
// Phase 0: z (128 x 2000 fp32) -> bf16 row-major (0.5 MB, L2-resident).
// =====================================================================
__global__ __launch_bounds__(256, 4) void convert_z_kernel(
    const float* __restrict__ zp, ushort* __restrict__ zb) {
  const int idx = (blockIdx.x * 256 + threadIdx.x) * 8;  // 125*256*8 = 256000
  int4 v = pack8(zp + idx);
  *(int4*)(zb + idx) = v;
}

// =====================================================================
// Phase 1: barrier-free split-K GEMM.
// hp[s][g][b] (bf16) = sum_{k in split s} W[g,k] * z[b,k]
// One wave per (16-group tile, k-split). A-frag = W rows (m=group, packed
// fp32->bf16 in-register), B-frag = z rows (bf16, direct from L2).
// MFMA D: row = q*4+reg = group, col = lane&15 = batch -> b-contiguous
// 32-B stores per quad. b_fc skipped: cancels under training-mode BN.
// 4375 waves, no __syncthreads anywhere -> no vmcnt(0) barrier drains.
// =====================================================================
__global__ __launch_bounds__(256, 4) void gemm_nobarrier_kernel(
    const ushort* __restrict__ zb, const float* __restrict__ wp,
    ushort* __restrict__ hp) {
  const int gw = (int)((blockIdx.x * 256 + threadIdx.x) >> 6);  // global wave
  if (gw >= NTILE * KSPL) return;
  const int lane = threadIdx.x & 63;
  const int tile = gw / KSPL;
  const int spl  = gw - tile * KSPL;
  const int g0   = tile * 16;
  const int q    = lane >> 4;
  const int cl   = lane & 15;

  f32x4 acc[8];
  const f32x4 vzero = {0.f, 0.f, 0.f, 0.f};
#pragma unroll
  for (int i = 0; i < 8; ++i) acc[i] = vzero;

  const float*  wrow = wp + (size_t)(g0 + cl) * LAT;  // A: W row for lane
  const ushort* zrow = zb + (size_t)cl * LAT;         // B: z row base for lane

#pragma unroll
  for (int c = 0; c < CPS; ++c) {
    const int k0 = (spl * CPS + c) * 32 + q * 8;  // lane's 8-elem k base
    const bool valid = (k0 < LAT);  // k0 % 8 == 0 -> chunk fully valid or not

    bf16x8 afr;
    if (valid) {
      int4 v = pack8(wrow + k0);
      afr = *(bf16x8*)&v;
    } else {
      int4 v = make_int4(0, 0, 0, 0);
      afr = *(bf16x8*)&v;
    }

    bf16x8 bfr[8];
#pragma unroll
    for (int nt = 0; nt < 8; ++nt) {
      if (valid)
        bfr[nt] = *(const bf16x8*)(zrow + (size_t)(nt * 16) * LAT + k0);
      else {
        int4 v = make_int4(0, 0, 0, 0);
        bfr[nt] = *(bf16x8*)&v;
      }
    }
#pragma unroll
    for (int nt = 0; nt < 8; ++nt)
      acc[nt] = __builtin_amdgcn_mfma_f32_16x16x32_bf16(afr, bfr[nt],
                                                        acc[nt], 0, 0, 0);
  }

  // store bf16 partials: hp[spl][g0 + q*4 + r][nt*16 + cl]
  ushort* base = hp + ((size_t)spl * NG + g0) * BATCH;
#pragma unroll
  for (int r = 0; r < 4; ++r) {
    ushort* rowp = base + (size_t)(q * 4 + r) * BATCH + cl;
#pragma unroll
    for (int nt = 0; nt < 8; ++nt)
      rowp[nt * 16] = f2bf(acc[nt][r]);
  }
}

// =====================================================================
// Phase 2: fused stats + expand. 32 lanes per group (8 groups/block);
// lane holds 4 batch elems (bf16x4 loads, b-contiguous). Sum 7 split
// partials -> BN stats via in-wave shuffle (masks <=16 stay in the 32-lane
// group) -> BN + leaky + outer(20) + leaky + sigmoid -> fp32 out.
// =====================================================================
__global__ __launch_bounds__(256, 4) void expand_kernel(
    const ushort* __restrict__ hp, const float* __restrict__ gammap,
    const float* __restrict__ betap, const float* __restrict__ convwp,
    const float* __restrict__ convbp, float* __restrict__ out) {
  const int tid = threadIdx.x;
  const int g   = blockIdx.x * 8 + (tid >> 5);
  const int bc  = (tid & 31) * 4;

  float4 hv = make_float4(0.f, 0.f, 0.f, 0.f);
#pragma unroll
  for (int s = 0; s < KSPL; ++s) {
    ushort4 v = *(const ushort4*)(hp + ((size_t)s * NG + g) * BATCH + bc);
    hv.x += bf2f(v.x); hv.y += bf2f(v.y);
    hv.z += bf2f(v.z); hv.w += bf2f(v.w);
  }

  // BN stats over the 32-lane group (128 batch values)
  float sm = hv.x + hv.y + hv.z + hv.w;
  float sq = hv.x * hv.x + hv.y * hv.y + hv.z * hv.z + hv.w * hv.w;
#pragma unroll
  for (int m = 1; m < 32; m <<= 1) {
    sm += __shfl_xor(sm, m);
    sq += __shfl_xor(sq, m);
  }
  float mean = sm * (1.f / 128.f);
  float var  = sq * (1.f / 128.f) - mean * mean;
  var = (var < 0.f) ? 0.f : var;
  float inv   = __builtin_amdgcn_rsqf(var + EPSV);
  float scale = inv * gammap[g];
  float shift = betap[g] - mean * scale;
  const float cb = convbp[g];

  float wv[KW];
  {
    const float4* pw = (const float4*)(convwp + (size_t)g * KW);
#pragma unroll
    for (int j = 0; j < 5; ++j) {
      float4 f = pw[j];
      wv[4 * j] = f.x; wv[4 * j + 1] = f.y;
      wv[4 * j + 2] = f.z; wv[4 * j + 3] = f.w;
    }
  }

  float hb[4] = {hv.x, hv.y, hv.z, hv.w};
#pragma unroll
  for (int i = 0; i < 4; ++i) {
    float h = hb[i] * scale + shift;
    h = fmaxf(h, h * 0.1f);  // leaky(0.1)
    float4 ov[5];
#pragma unroll
    for (int j = 0; j < 5; ++j) {
      float y0 = h * wv[4 * j]     + cb;
      float y1 = h * wv[4 * j + 1] + cb;
      float y2 = h * wv[4 * j + 2] + cb;
      float y3 = h * wv[4 * j + 3] + cb;
      y0 = fmaxf(y0, y0 * 0.1f);
      y1 = fmaxf(y1, y1 * 0.1f);
      y2 = fmaxf(y2, y2 * 0.1f);
      y3 = fmaxf(y3, y3 * 0.1f);
      ov[j].x = __builtin_amdgcn_rcpf(1.f + exp2f(y0 * -1.44269504f));
      ov[j].y = __builtin_amdgcn_rcpf(1.f + exp2f(y1 * -1.44269504f));
      ov[j].z = __builtin_amdgcn_rcpf(1.f + exp2f(y2 * -1.44269504f));
      ov[j].w = __builtin_amdgcn_rcpf(1.f + exp2f(y3 * -1.44269504f));
    }
    float4* po = (float4*)(out + (size_t)(bc + i) * OUTW + (size_t)g * KW);
#pragma unroll
    for (int j = 0; j < 5; ++j) po[j] = ov[j];
  }
}

// =====================================================================
// Fallback (ws too small): round-2 fused kernel, known-correct.
// =====================================================================
#define FBK 64
__global__ __launch_bounds__(256, 2) void fused_decoder_kernel(
    const float* __restrict__ zp, const float* __restrict__ wp,
    const float* __restrict__ gammap, const float* __restrict__ betap,
    const float* __restrict__ convwp, const float* __restrict__ convbp,
    float* __restrict__ out) {
  const int tid = threadIdx.x;
  const int g0  = blockIdx.x * 32;

  __shared__ ushort As[BATCH * FBK];
  __shared__ ushort Bs[32 * FBK];
  __shared__ float statS[2][2][16];
  __shared__ float statQ[2][2][16];

  const int lane = tid & 63;
  const int w    = tid >> 6;
  const int wm   = w & 1;
  const int wn   = w >> 1;
  const int q    = lane >> 4;
  const int cl   = lane & 15;

  f32x4 acc[4];
  const f32x4 vzero = {0.f, 0.f, 0.f, 0.f};
#pragma unroll
  for (int i = 0; i < 4; ++i) acc[i] = vzero;

  for (int it = 0; it < 32; ++it) {
    const int k0 = it * FBK;
    __syncthreads();
#pragma unroll
    for (int i = 0; i < 4; ++i) {
      int c = i * 256 + tid;
      int r = c >> 3, sc = c & 7;
      int gk = k0 + sc * 8;
      int4 v = make_int4(0, 0, 0, 0);
      if (gk < LAT) v = pack8(zp + (size_t)r * LAT + gk);
      *(int4*)&As[r * FBK + ((sc ^ (r & 7)) << 3)] = v;
    }
    {
      int r = tid >> 3, sc = tid & 7;
      int g  = g0 + r;
      int gk = k0 + sc * 8;
      int4 v = make_int4(0, 0, 0, 0);
      if (gk < LAT && g < NG) v = pack8(wp + (size_t)g * LAT + gk);
      *(int4*)&Bs[r * FBK + ((sc ^ (r & 7)) << 3)] = v;
    }
    __syncthreads();
#pragma unroll
    for (int kk = 0; kk < 2; ++kk) {
      int sc = kk * 4 + q;
      bf16x8 af[4], bfr;
#pragma unroll
      for (int mt = 0; mt < 4; ++mt) {
        int ra = wm * 64 + mt * 16 + cl;
        af[mt] = *(const bf16x8*)&As[ra * FBK + ((sc ^ (ra & 7)) << 3)];
      }
      {
        int rb = wn * 16 + cl;
        bfr = *(const bf16x8*)&Bs[rb * FBK + ((sc ^ (rb & 7)) << 3)];
      }
#pragma unroll
      for (int mt = 0; mt < 4; ++mt)
        acc[mt] = __builtin_amdgcn_mfma_f32_16x16x32_bf16(af[mt], bfr,
                                                          acc[mt], 0, 0, 0);
    }
  }

  float s = 0.f, ss = 0.f;
#pragma unroll
  for (int mt = 0; mt < 4; ++mt)
#pragma unroll
    for (int r = 0; r < 4; ++r) {
      float v = acc[mt][r];
      s += v; ss += v * v;
    }
  s += __shfl_xor(s, 16); ss += __shfl_xor(ss, 16);
  s += __shfl_xor(s, 32); ss += __shfl_xor(ss, 32);
  if (q == 0) { statS[wm][wn][cl] = s; statQ[wm][wn][cl] = ss; }
  __syncthreads();

  const int gcol = g0 + wn * 16 + cl;
  const int gc   = (gcol < NG) ? gcol : (NG - 1);
  float S = statS[0][wn][cl] + statS[1][wn][cl];
  float Q = statQ[0][wn][cl] + statQ[1][wn][cl];
  float mean = S * (1.f / 128.f);
  float var  = Q * (1.f / 128.f) - mean * mean;
  var = (var < 0.f) ? 0.f : var;
  float inv = __builtin_amdgcn_rsqf(var + EPSV);
  float ga = gammap[gc], be = betap[gc], cb = convbp[gc];
  float wv[KW];
  {
    const float4* pw = (const float4*)(convwp + (size_t)gc * KW);
#pragma unroll
    for (int j = 0; j < 5; ++j) {
      float4 f = pw[j];
      wv[4 * j] = f.x; wv[4 * j + 1] = f.y;
      wv[4 * j + 2] = f.z; wv[4 * j + 3] = f.w;
    }
  }
  float scale = inv * ga;
  float shift = be - mean * scale;
  const bool ok = (gcol < NG);
#pragma unroll
  for (int mt = 0; mt < 4; ++mt) {
#pragma unroll
    for (int r = 0; r < 4; ++r) {
      float h = acc[mt][r] * scale + shift;
      h = fmaxf(h, h * 0.1f);
      int b = wm * 64 + mt * 16 + q * 4 + r;
      float4 ov[5];
#pragma unroll
      for (int j = 0; j < 5; ++j) {
        float y0 = h * wv[4 * j]     + cb;
        float y1 = h * wv[4 * j + 1] + cb;
        float y2 = h * wv[4 * j + 2] + cb;
        float y3 = h * wv[4 * j + 3] + cb;
        y0 = fmaxf(y0, y0 * 0.1f);
        y1 = fmaxf(y1, y1 * 0.1f);
        y2 = fmaxf(y2, y2 * 0.1f);
        y3 = fmaxf(y3, y3 * 0.1f);
        ov[j].x = __builtin_amdgcn_rcpf(1.f + exp2f(y0 * -1.44269504f));
        ov[j].y = __builtin_amdgcn_rcpf(1.f + exp2f(y1 * -1.44269504f));
        ov[j].z = __builtin_amdgcn_rcpf(1.f + exp2f(y2 * -1.44269504f));
        ov[j].w = __builtin_amdgcn_rcpf(1.f + exp2f(y3 * -1.44269504f));
      }
      if (ok) {
        float4* po = (float4*)(out + (size_t)b * OUTW + (size_t)gcol * KW);
#pragma unroll
        for (int j = 0; j < 5; ++j) po[j] = ov[j];
      }
    }
  }
}

extern "C" void kernel_launch(void* const* d_in, const int* in_sizes, int n_in,
                              void* d_out, int out_size, void* d_ws, size_t ws_size,
                              hipStream_t stream) {
  const float* z     = (const float*)d_in[0];
  const float* W     = (const float*)d_in[1];
  // d_in[2] = b_fc: unused — cancels under training-mode batchnorm
  const float* gamma = (const float*)d_in[3];
  const float* beta  = (const float*)d_in[4];
  const float* convw = (const float*)d_in[5];
  const float* convb = (const float*)d_in[6];
  float* out = (float*)d_out;

  const size_t hp_elems = (size_t)KSPL * NG * BATCH;          // 8,960,000 bf16
  const size_t zb_elems = (size_t)BATCH * LAT;                // 256,000 bf16
  const size_t need = (hp_elems + zb_elems) * sizeof(ushort); // ~18.4 MB

  if (ws_size >= need) {
    ushort* hp = (ushort*)d_ws;
    ushort* zb = hp + hp_elems;  // byte offset 17,920,000 — 16B-aligned

    convert_z_kernel<<<BATCH * LAT / (256 * 8), 256, 0, stream>>>(z, zb);
    const int nwaves  = NTILE * KSPL;                 // 4375
    const int nblocks = (nwaves + 3) / 4;             // 1094 (256 thr = 4 waves)
    gemm_nobarrier_kernel<<<nblocks, 256, 0, stream>>>(zb, W, hp);
    expand_kernel<<<NG / 8, 256, 0, stream>>>(hp, gamma, beta, convw,
                                              convb, out);
  } else {
    fused_decoder_kernel<<<(NG + 31) / 32, 256, 0, stream>>>(
        z, W, gamma, beta, convw, convb, out);
  }
}